// Round 1
// baseline (114.636 us; speedup 1.0000x reference)
//
#include <hip/hip_runtime.h>

// InvWarpFlow: out[b,y,x,c] = bilinear(img[b], (y + flow[b,y,x,0], x + flow[b,y,x,1]))
// (reference is dense_image_warp(img, -flow), so query = grid + flow)
// img:  [16,256,512,32] f32
// flow: [16,256,512,2]  f32
// out:  [16,256,512,32] f32

__global__ __launch_bounds__(256) void InvWarpFlow_kernel(
    const float* __restrict__ img,
    const float* __restrict__ flow,
    float* __restrict__ out)
{
    constexpr int H = 256, W = 512, C = 32;
    // 8 threads per pixel, 4 channels (float4) per thread.
    int t   = blockIdx.x * blockDim.x + threadIdx.x;   // [0, B*H*W*8)
    int cg  = t & 7;                                   // channel group
    int pix = t >> 3;                                  // [0, B*H*W)
    int x   = pix & (W - 1);
    int yb  = pix >> 9;                                // pix / W
    int y   = yb & (H - 1);
    int b   = yb >> 8;

    // flow[pix] = (dy, dx); query = grid + flow
    const float2 f = *reinterpret_cast<const float2*>(flow + (size_t)pix * 2);
    float qy = (float)y + f.x;
    float qx = (float)x + f.y;

    float fy = fminf(fmaxf(floorf(qy), 0.0f), (float)(H - 2));
    float fx = fminf(fmaxf(floorf(qx), 0.0f), (float)(W - 2));
    float ay = fminf(fmaxf(qy - fy, 0.0f), 1.0f);
    float ax = fminf(fmaxf(qx - fx, 0.0f), 1.0f);
    int iy = (int)fy;
    int ix = (int)fx;

    const float* base = img + ((((size_t)b * H + iy) * W + ix) * C) + cg * 4;
    float4 tl = *reinterpret_cast<const float4*>(base);
    float4 tr = *reinterpret_cast<const float4*>(base + C);
    float4 bl = *reinterpret_cast<const float4*>(base + (size_t)W * C);
    float4 br = *reinterpret_cast<const float4*>(base + (size_t)W * C + C);

    float4 o;
    {
        float top, bot;
        top = tl.x + (tr.x - tl.x) * ax;
        bot = bl.x + (br.x - bl.x) * ax;
        o.x = top + (bot - top) * ay;
        top = tl.y + (tr.y - tl.y) * ax;
        bot = bl.y + (br.y - bl.y) * ax;
        o.y = top + (bot - top) * ay;
        top = tl.z + (tr.z - tl.z) * ax;
        bot = bl.z + (br.z - bl.z) * ax;
        o.z = top + (bot - top) * ay;
        top = tl.w + (tr.w - tl.w) * ax;
        bot = bl.w + (br.w - bl.w) * ax;
        o.w = top + (bot - top) * ay;
    }

    *reinterpret_cast<float4*>(out + (size_t)pix * C + cg * 4) = o;
}

extern "C" void kernel_launch(void* const* d_in, const int* in_sizes, int n_in,
                              void* d_out, int out_size, void* d_ws, size_t ws_size,
                              hipStream_t stream) {
    const float* img  = (const float*)d_in[0];
    const float* flow = (const float*)d_in[1];
    float* out = (float*)d_out;

    constexpr int B = 16, H = 256, W = 512;
    int total_threads = B * H * W * 8;          // 16,777,216
    int block = 256;
    int grid  = total_threads / block;          // 65,536
    InvWarpFlow_kernel<<<grid, block, 0, stream>>>(img, flow, out);
}